// Round 1
// baseline (2612.764 us; speedup 1.0000x reference)
//
#include <hip/hip_runtime.h>
#include <cstdint>
#include <cstddef>
#include <cmath>

#define DI __device__ __forceinline__

// Flip to 0 if absmax lands ~0.2-0.5 (would indicate legacy non-partitionable threefry)
#define NOISE_PARTITIONABLE 1

constexpr int B_ = 8;
constexpr int F0_ = 64;
constexpr int FIN_ = 192;    // 3*F0
constexpr int FOUT_ = 128;
constexpr int LAT_ = 512;
constexpr int P_ = 45376;    // FH*FIN + FH + FOUT*FH + FOUT + FOUT*FIN + FOUT
constexpr int NLAY_ = 16;
constexpr int MAXHW_ = 16384;

// ks sub-offsets (per batch row of P_ floats)
constexpr int KO_W0 = 0;       // (64,192)
constexpr int KO_B0 = 12288;   // (64,)
constexpr int KO_W1 = 12352;   // (128,64)
constexpr int KO_B1 = 20544;   // (128,)
constexpr int KO_WS = 20672;   // (128,192)
constexpr int KO_BS = 45248;   // (128,)

// workspace layout (float offsets)
constexpr size_t OFF_LATC = 0;                                      // 16*8*512
constexpr size_t OFF_KS   = OFF_LATC + (size_t)NLAY_ * B_ * LAT_;   // 16*8*P
constexpr size_t OFF_OUT  = OFF_KS + (size_t)NLAY_ * B_ * P_;       // 8*64*16384
constexpr size_t OFF_P    = OFF_OUT + (size_t)B_ * F0_ * MAXHW_;    // 8*192*16384
constexpr size_t OFF_TMP  = OFF_P;                                  // alias (resize tmp <= p size)

// ---------------- threefry2x32 (JAX order) ----------------
DI void tf_cipher(uint32_t k0, uint32_t k1, uint32_t x0, uint32_t x1,
                  uint32_t& o0, uint32_t& o1) {
  const uint32_t ks2 = k0 ^ k1 ^ 0x1BD11BDAu;
  uint32_t a = x0 + k0, b = x1 + k1;
#define TFR(r) { a += b; b = (b << (r)) | (b >> (32 - (r))); b ^= a; }
  TFR(13) TFR(15) TFR(26) TFR(6)  a += k1;  b += ks2 + 1u;
  TFR(17) TFR(29) TFR(16) TFR(24) a += ks2; b += k0 + 2u;
  TFR(13) TFR(15) TFR(26) TFR(6)  a += k0;  b += k1 + 3u;
  TFR(17) TFR(29) TFR(16) TFR(24) a += k1;  b += ks2 + 4u;
  TFR(13) TFR(15) TFR(26) TFR(6)  a += ks2; b += k0 + 5u;
#undef TFR
  o0 = a; o1 = b;
}

static void host_tf_cipher(uint32_t k0, uint32_t k1, uint32_t x0, uint32_t x1,
                           uint32_t& o0, uint32_t& o1) {
  const uint32_t ks2 = k0 ^ k1 ^ 0x1BD11BDAu;
  uint32_t a = x0 + k0, b = x1 + k1;
#define TFR(r) { a += b; b = (b << (r)) | (b >> (32 - (r))); b ^= a; }
  TFR(13) TFR(15) TFR(26) TFR(6)  a += k1;  b += ks2 + 1u;
  TFR(17) TFR(29) TFR(16) TFR(24) a += ks2; b += k0 + 2u;
  TFR(13) TFR(15) TFR(26) TFR(6)  a += k0;  b += k1 + 3u;
  TFR(17) TFR(29) TFR(16) TFR(24) a += k1;  b += ks2 + 4u;
  TFR(13) TFR(15) TFR(26) TFR(6)  a += ks2; b += k0 + 5u;
#undef TFR
  o0 = a; o1 = b;
}

// ---------------- erfinv (Giles / XLA ErfInv32) ----------------
DI float erfinv_f(float x) {
  float w = -log1pf(-x * x);
  float p;
  if (w < 5.0f) {
    w = w - 2.5f;
    p = 2.81022636e-08f;
    p = fmaf(p, w, 3.43273939e-07f);
    p = fmaf(p, w, -3.5233877e-06f);
    p = fmaf(p, w, -4.39150654e-06f);
    p = fmaf(p, w, 0.00021858087f);
    p = fmaf(p, w, -0.00125372503f);
    p = fmaf(p, w, -0.00417768164f);
    p = fmaf(p, w, 0.246640727f);
    p = fmaf(p, w, 1.50140941f);
  } else {
    w = sqrtf(w) - 3.0f;
    p = -0.000200214257f;
    p = fmaf(p, w, 0.000100950558f);
    p = fmaf(p, w, 0.00134934322f);
    p = fmaf(p, w, -0.00367342844f);
    p = fmaf(p, w, 0.00573950773f);
    p = fmaf(p, w, -0.0076224613f);
    p = fmaf(p, w, 0.00943887047f);
    p = fmaf(p, w, 1.00167406f);
    p = fmaf(p, w, 2.83297682f);
  }
  return p * x;
}

DI float noise_val(uint32_t k0, uint32_t k1, uint32_t idx, uint32_t halfn) {
  uint32_t o0, o1, bits;
#if NOISE_PARTITIONABLE
  (void)halfn;
  tf_cipher(k0, k1, 0u, idx, o0, o1);
  bits = o0 ^ o1;
#else
  uint32_t j = (idx < halfn) ? idx : idx - halfn;
  tf_cipher(k0, k1, j, j + halfn, o0, o1);
  bits = (idx < halfn) ? o0 : o1;
#endif
  float f = __uint_as_float((bits >> 9) | 0x3f800000u) - 1.0f;
  const float lo = -0.99999994f;  // nextafter(-1, 0)
  float u = fmaxf(lo, fmaf(f, 2.0f, lo));
  return 1.41421354f * erfinv_f(u);  // float(sqrt(2)) * erfinv(u)
}

// ---------------- seed broadcast ----------------
__global__ __launch_bounds__(256) void k_seed(const float* __restrict__ seed,
                                              float* __restrict__ outb) {
  int idx = blockIdx.x * 256 + threadIdx.x;  // < 8*64*256
  outb[idx] = seed[idx & (F0_ * 256 - 1)];
}

// ---------------- latc = lat @ lat_exp_w[c]^T + b ----------------
__global__ __launch_bounds__(256) void k_latc(const float* __restrict__ lat,
                                              const float* __restrict__ wexp,
                                              const float* __restrict__ bexp,
                                              float* __restrict__ latc) {
  const int c = blockIdx.x;
  const int tid = threadIdx.x;
  __shared__ float latS[B_][LAT_];
  for (int i = tid; i < B_ * LAT_; i += 256) latS[i >> 9][i & 511] = lat[i];
  __syncthreads();
  for (int o = tid; o < LAT_; o += 256) {
    float acc[B_] = {0, 0, 0, 0, 0, 0, 0, 0};
    const float* wr = wexp + ((size_t)c * LAT_ + o) * LAT_;
    for (int k = 0; k < LAT_; k += 4) {
      float4 w4 = *(const float4*)(wr + k);
#pragma unroll
      for (int b = 0; b < B_; ++b) {
        acc[b] = fmaf(w4.x, latS[b][k + 0], acc[b]);
        acc[b] = fmaf(w4.y, latS[b][k + 1], acc[b]);
        acc[b] = fmaf(w4.z, latS[b][k + 2], acc[b]);
        acc[b] = fmaf(w4.w, latS[b][k + 3], acc[b]);
      }
    }
    const float bb = bexp[c * LAT_ + o];
#pragma unroll
    for (int b = 0; b < B_; ++b)
      latc[((size_t)c * B_ + b) * LAT_ + o] = acc[b] + bb;
  }
}

// ---------------- ks = latc @ dyna_w^T + dyna_b  (M=128, N=45376, K=512) ----------------
__global__ __launch_bounds__(256) void k_ks(const float* __restrict__ latc,
                                            const float* __restrict__ dyna_w,
                                            const float* __restrict__ dyna_b,
                                            float* __restrict__ ks) {
  const int n0 = blockIdx.x * 64;
  const int tid = threadIdx.x;
  const int tx = tid & 15, ty = tid >> 4;
  __shared__ __align__(16) float As[16][128];
  __shared__ __align__(16) float Bs[16][64];
  float acc[8][4];
#pragma unroll
  for (int i = 0; i < 8; ++i)
#pragma unroll
    for (int j = 0; j < 4; ++j) acc[i][j] = 0.f;

  const int m_f = tid >> 1, kq_f = tid & 1;
  const int n_f = tid >> 2, kq4_f = tid & 3;

  for (int kc = 0; kc < LAT_; kc += 16) {
    __syncthreads();
    {
      const float* src = latc + (size_t)m_f * LAT_ + kc + kq_f * 8;
      float4 a0 = *(const float4*)(src);
      float4 a1 = *(const float4*)(src + 4);
      int kb = kq_f * 8;
      As[kb + 0][m_f] = a0.x; As[kb + 1][m_f] = a0.y; As[kb + 2][m_f] = a0.z; As[kb + 3][m_f] = a0.w;
      As[kb + 4][m_f] = a1.x; As[kb + 5][m_f] = a1.y; As[kb + 6][m_f] = a1.z; As[kb + 7][m_f] = a1.w;
    }
    {
      const float4 v = *(const float4*)(dyna_w + (size_t)(n0 + n_f) * LAT_ + kc + kq4_f * 4);
      int kb = kq4_f * 4;
      Bs[kb + 0][n_f] = v.x; Bs[kb + 1][n_f] = v.y; Bs[kb + 2][n_f] = v.z; Bs[kb + 3][n_f] = v.w;
    }
    __syncthreads();
#pragma unroll
    for (int k = 0; k < 16; ++k) {
      const float4 xv = *(const float4*)&Bs[k][tx * 4];
      const float4 wa = *(const float4*)&As[k][ty * 8];
      const float4 wb = *(const float4*)&As[k][ty * 8 + 4];
      const float wv[8] = {wa.x, wa.y, wa.z, wa.w, wb.x, wb.y, wb.z, wb.w};
#pragma unroll
      for (int i = 0; i < 8; ++i) {
        acc[i][0] = fmaf(wv[i], xv.x, acc[i][0]);
        acc[i][1] = fmaf(wv[i], xv.y, acc[i][1]);
        acc[i][2] = fmaf(wv[i], xv.z, acc[i][2]);
        acc[i][3] = fmaf(wv[i], xv.w, acc[i][3]);
      }
    }
  }
  const float4 bv = *(const float4*)(dyna_b + n0 + tx * 4);
#pragma unroll
  for (int i = 0; i < 8; ++i) {
    const int m = ty * 8 + i;
    float4 o;
    o.x = acc[i][0] + bv.x; o.y = acc[i][1] + bv.y;
    o.z = acc[i][2] + bv.z; o.w = acc[i][3] + bv.w;
    *(float4*)(ks + (size_t)m * P_ + n0 + tx * 4) = o;
  }
}

// ---------------- p = inorm(concat(dwx, dwy, out)) ----------------
DI void conv9(const float* __restrict__ pl, int h, int w, int H, int W,
              float& vx, float& vy, float& vi) {
  const bool up = h > 0, dn = h < H - 1, lf = w > 0, rt = w < W - 1;
  const float* r0 = pl + (size_t)(h - 1) * W;
  const float* r1 = pl + (size_t)h * W;
  const float* r2 = pl + (size_t)(h + 1) * W;
  float c00 = (up && lf) ? r0[w - 1] : 0.f;
  float c01 = up ? r0[w] : 0.f;
  float c02 = (up && rt) ? r0[w + 1] : 0.f;
  float c10 = lf ? r1[w - 1] : 0.f;
  float c11v = r1[w];
  float c12 = rt ? r1[w + 1] : 0.f;
  float c20 = (dn && lf) ? r2[w - 1] : 0.f;
  float c21 = dn ? r2[w] : 0.f;
  float c22 = (dn && rt) ? r2[w + 1] : 0.f;
  vx = (c02 - c00 + 2.f * (c12 - c10) + (c22 - c20)) * 0.125f;
  vy = (c20 - c00 + 2.f * (c21 - c01) + (c22 - c02)) * 0.125f;
  vi = c11v;
}

__global__ __launch_bounds__(256) void k_prep(const float* __restrict__ outb,
                                              float* __restrict__ p,
                                              int H, int W, int logW) {
  const int bc = blockIdx.x;
  const int b = bc >> 6, ch = bc & 63;
  const int HW = H * W;
  const float* __restrict__ pl = outb + (size_t)(b * F0_ + ch) * HW;
  const int tid = threadIdx.x;

  float s[6] = {0, 0, 0, 0, 0, 0};
  for (int px = tid; px < HW; px += 256) {
    const int h = px >> logW, w = px & (W - 1);
    float vx, vy, vi;
    conv9(pl, h, w, H, W, vx, vy, vi);
    s[0] += vx; s[1] += vx * vx;
    s[2] += vy; s[3] += vy * vy;
    s[4] += vi; s[5] += vi * vi;
  }
  __shared__ float red[4][6];
  __shared__ float fin[6];
#pragma unroll
  for (int i = 0; i < 6; ++i)
#pragma unroll
    for (int off = 32; off > 0; off >>= 1)
      s[i] += __shfl_down(s[i], off, 64);
  const int lane = tid & 63, wv = tid >> 6;
  if (lane == 0) {
#pragma unroll
    for (int i = 0; i < 6; ++i) red[wv][i] = s[i];
  }
  __syncthreads();
  if (tid < 6) fin[tid] = red[0][tid] + red[1][tid] + red[2][tid] + red[3][tid];
  __syncthreads();
  const float inv = 1.0f / (float)HW;
  const float mx = fin[0] * inv, my = fin[2] * inv, mi = fin[4] * inv;
  const float rx = rsqrtf(fmaxf(fin[1] * inv - mx * mx, 0.f) + 1e-5f);
  const float ry = rsqrtf(fmaxf(fin[3] * inv - my * my, 0.f) + 1e-5f);
  const float ri = rsqrtf(fmaxf(fin[5] * inv - mi * mi, 0.f) + 1e-5f);

  float* __restrict__ d0 = p + (size_t)(b * FIN_ + ch) * HW;
  float* __restrict__ d1 = p + (size_t)(b * FIN_ + 64 + ch) * HW;
  float* __restrict__ d2 = p + (size_t)(b * FIN_ + 128 + ch) * HW;
  for (int px = tid; px < HW; px += 256) {
    const int h = px >> logW, w = px & (W - 1);
    float vx, vy, vi;
    conv9(pl, h, w, H, W, vx, vy, vi);
    d0[px] = (vx - mx) * rx;
    d1[px] = (vy - my) * ry;
    d2[px] = (vi - mi) * ri;
  }
}

// ---------------- fused main layer kernel ----------------
#define INNER16(XBASE)                                            \
  _Pragma("unroll")                                               \
  for (int k = 0; k < 16; ++k) {                                  \
    const float4 xv = *(const float4*)((XBASE) + k * 64 + tx * 4);\
    const float4 wa = *(const float4*)&Ws[k][ty * 8];             \
    const float4 wb = *(const float4*)&Ws[k][ty * 8 + 4];         \
    const float wv[8] = {wa.x, wa.y, wa.z, wa.w, wb.x, wb.y, wb.z, wb.w}; \
    _Pragma("unroll")                                             \
    for (int i = 0; i < 8; ++i) {                                 \
      acc[i][0] = fmaf(wv[i], xv.x, acc[i][0]);                   \
      acc[i][1] = fmaf(wv[i], xv.y, acc[i][1]);                   \
      acc[i][2] = fmaf(wv[i], xv.z, acc[i][2]);                   \
      acc[i][3] = fmaf(wv[i], xv.w, acc[i][3]);                   \
    }                                                             \
  }

__global__ __launch_bounds__(256) void k_main(
    const float* __restrict__ p, float* __restrict__ out,
    const float* __restrict__ ks_layer,
    const float* __restrict__ conv0_w, const float* __restrict__ conv0_b,
    const float* __restrict__ conv1_w, const float* __restrict__ conv1_b,
    const float* __restrict__ convs_w,
    const float* __restrict__ noise_w_c,
    const float* __restrict__ leak_ptr,
    int HW, unsigned key0, unsigned key1) {
  const int b = blockIdx.y;
  const int px0 = blockIdx.x * 64;
  const int tid = threadIdx.x;
  const int tx = tid & 15, ty = tid >> 4;

  __shared__ __align__(16) float Xs[16][64];
  __shared__ __align__(16) float Ws[16][128];
  __shared__ __align__(16) float Hs[128][64];
  __shared__ float noiseS[64];

  const float* __restrict__ ksb = ks_layer + (size_t)b * P_;
  const float* __restrict__ pb = p + (size_t)b * FIN_ * HW + px0;
  float* __restrict__ outb = out + (size_t)b * F0_ * HW + px0;

  const int fx = tid & 63;   // fill pixel
  const int fw = tid >> 6;   // wave id
  const int woc = tid >> 1;  // fill oc
  const int wkq = tid & 1;

  float acc[8][4];
#pragma unroll
  for (int i = 0; i < 8; ++i)
#pragma unroll
    for (int j = 0; j < 4; ++j) acc[i][j] = 0.f;

  // ===== GEMM1: h = [conv0_w ; w0] @ lrelu(p)   (K = 192)
  for (int kc = 0; kc < FIN_; kc += 16) {
    __syncthreads();
#pragma unroll
    for (int r = 0; r < 4; ++r) {
      const int k = fw * 4 + r;
      const float v = pb[(size_t)(kc + k) * HW + fx];
      Xs[k][fx] = (v > 0.f) ? v : 0.2f * v;
    }
    {
      const float* src = (woc < 64)
          ? (conv0_w + woc * FIN_ + kc + wkq * 8)
          : (ksb + KO_W0 + (woc - 64) * FIN_ + kc + wkq * 8);
      const float4 a0 = *(const float4*)(src);
      const float4 a1 = *(const float4*)(src + 4);
      const int kb = wkq * 8;
      Ws[kb + 0][woc] = a0.x; Ws[kb + 1][woc] = a0.y; Ws[kb + 2][woc] = a0.z; Ws[kb + 3][woc] = a0.w;
      Ws[kb + 4][woc] = a1.x; Ws[kb + 5][woc] = a1.y; Ws[kb + 6][woc] = a1.z; Ws[kb + 7][woc] = a1.w;
    }
    __syncthreads();
    INNER16(&Xs[0][0])
  }
  __syncthreads();
  // bias + lrelu -> Hs ; reset acc
#pragma unroll
  for (int i = 0; i < 8; ++i) {
    const int oc = ty * 8 + i;
    const float bia = (oc < 64) ? conv0_b[oc] : ksb[KO_B0 + oc - 64];
#pragma unroll
    for (int j = 0; j < 4; ++j) {
      float hv = acc[i][j] + bia;
      Hs[oc][tx * 4 + j] = (hv > 0.f) ? hv : 0.2f * hv;
      acc[i][j] = 0.f;
    }
  }

  // ===== GEMM2 part A: (convs_w + ws) @ p   (K = 192)
  for (int kc = 0; kc < FIN_; kc += 16) {
    __syncthreads();
#pragma unroll
    for (int r = 0; r < 4; ++r) {
      const int k = fw * 4 + r;
      Xs[k][fx] = pb[(size_t)(kc + k) * HW + fx];
    }
    {
      const float* s1 = convs_w + woc * FIN_ + kc + wkq * 8;
      const float* s2 = ksb + KO_WS + woc * FIN_ + kc + wkq * 8;
      const float4 a0 = *(const float4*)(s1);
      const float4 a1 = *(const float4*)(s1 + 4);
      const float4 b0 = *(const float4*)(s2);
      const float4 b1 = *(const float4*)(s2 + 4);
      const int kb = wkq * 8;
      Ws[kb + 0][woc] = a0.x + b0.x; Ws[kb + 1][woc] = a0.y + b0.y;
      Ws[kb + 2][woc] = a0.z + b0.z; Ws[kb + 3][woc] = a0.w + b0.w;
      Ws[kb + 4][woc] = a1.x + b1.x; Ws[kb + 5][woc] = a1.y + b1.y;
      Ws[kb + 6][woc] = a1.z + b1.z; Ws[kb + 7][woc] = a1.w + b1.w;
    }
    __syncthreads();
    INNER16(&Xs[0][0])
  }

  // ===== GEMM2 part B: 0.1*[conv1_w | w1] @ lrelu(h)   (K = 128, from Hs)
  for (int kc = 0; kc < FOUT_; kc += 16) {
    __syncthreads();
    {
      const int kk = kc + wkq * 8;
      const float* src = (kk < 64) ? (conv1_w + woc * 64 + kk)
                                   : (ksb + KO_W1 + woc * 64 + kk - 64);
      const float4 a0 = *(const float4*)(src);
      const float4 a1 = *(const float4*)(src + 4);
      const int kb = wkq * 8;
      Ws[kb + 0][woc] = 0.1f * a0.x; Ws[kb + 1][woc] = 0.1f * a0.y;
      Ws[kb + 2][woc] = 0.1f * a0.z; Ws[kb + 3][woc] = 0.1f * a0.w;
      Ws[kb + 4][woc] = 0.1f * a1.x; Ws[kb + 5][woc] = 0.1f * a1.y;
      Ws[kb + 6][woc] = 0.1f * a1.z; Ws[kb + 7][woc] = 0.1f * a1.w;
    }
    __syncthreads();
    INNER16(&Hs[kc][0])
  }

  // bias2, write o128 tile into Hs (h no longer needed)
  __syncthreads();
#pragma unroll
  for (int i = 0; i < 8; ++i) {
    const int oc = ty * 8 + i;
    const float b2 = ksb[KO_BS + oc] + 0.1f * (conv1_b[oc] + ksb[KO_B1 + oc]);
#pragma unroll
    for (int j = 0; j < 4; ++j)
      Hs[oc][tx * 4 + j] = acc[i][j] + b2;
  }
  __syncthreads();
  if (tid < 64)
    noiseS[tid] = noise_val(key0, key1, (unsigned)(b * HW + px0 + tid),
                            (unsigned)(4 * HW));
  __syncthreads();

  const float lfv = fminf(fmaxf(leak_ptr[0], 0.001f), 1000.0f);
  const int px = tid & 63;
  const int cg = tid >> 6;
#pragma unroll
  for (int m = 0; m < 16; ++m) {
    const int ch = cg * 16 + m;
    const float a = Hs[ch][px];
    const float g = Hs[ch + 64][px];
    const float og = a * (1.0f / (1.0f + expf(-g)));
    const float val = og + noise_w_c[ch] * noiseS[px];
    outb[(size_t)ch * HW + px] += lfv * val;
  }
}

// ---------------- bilinear 2x resize (jax.image.resize semantics) ----------------
__global__ __launch_bounds__(256) void k_resize(const float* __restrict__ src,
                                                float* __restrict__ dst,
                                                int H, int W) {
  const int OW = 2 * W;
  const int OHW = 4 * H * W;
  const int idx = blockIdx.x * 256 + threadIdx.x;
  if (idx >= B_ * F0_ * OHW) return;
  const int plane = idx / OHW;
  const int opx = idx - plane * OHW;
  const int oh = opx / OW, ow = opx - oh * OW;
  const float shf = 0.5f * oh - 0.25f;
  const float swf = 0.5f * ow - 0.25f;
  int h0 = (int)floorf(shf); const float fh = shf - h0;
  int w0 = (int)floorf(swf); const float fw = swf - w0;
  int h1 = min(h0 + 1, H - 1); h0 = max(h0, 0);
  int w1 = min(w0 + 1, W - 1); w0 = max(w0, 0);
  const float* pl = src + (size_t)plane * H * W;
  const float v00 = pl[h0 * W + w0], v01 = pl[h0 * W + w1];
  const float v10 = pl[h1 * W + w0], v11 = pl[h1 * W + w1];
  dst[idx] = (1.f - fh) * ((1.f - fw) * v00 + fw * v01) +
             fh * ((1.f - fw) * v10 + fw * v11);
}

// ---------------- gaussian 3x3 depthwise (zero pad) ----------------
__global__ __launch_bounds__(256) void k_gauss(const float* __restrict__ src,
                                               float* __restrict__ dst,
                                               int H, int W,
                                               float wc, float we, float wm) {
  const int HW = H * W;
  const int idx = blockIdx.x * 256 + threadIdx.x;
  if (idx >= B_ * F0_ * HW) return;
  const int plane = idx / HW;
  const int px = idx - plane * HW;
  const int h = px / W, w = px - h * W;
  const float* pl = src + (size_t)plane * HW;
  const bool up = h > 0, dn = h < H - 1, lf = w > 0, rt = w < W - 1;
  const float* r0 = pl + (size_t)(h - 1) * W;
  const float* r1 = pl + (size_t)h * W;
  const float* r2 = pl + (size_t)(h + 1) * W;
  const float c00 = (up && lf) ? r0[w - 1] : 0.f;
  const float c01 = up ? r0[w] : 0.f;
  const float c02 = (up && rt) ? r0[w + 1] : 0.f;
  const float c10 = lf ? r1[w - 1] : 0.f;
  const float c11v = r1[w];
  const float c12 = rt ? r1[w + 1] : 0.f;
  const float c20 = (dn && lf) ? r2[w - 1] : 0.f;
  const float c21 = dn ? r2[w] : 0.f;
  const float c22 = (dn && rt) ? r2[w + 1] : 0.f;
  dst[idx] = wc * (c00 + c02 + c20 + c22) + we * (c01 + c10 + c12 + c21) + wm * c11v;
}

// ---------------- final 1x1 conv + clip ----------------
__global__ __launch_bounds__(256) void k_final(const float* __restrict__ outbuf,
                                               const float* __restrict__ out_w,
                                               const float* __restrict__ out_b,
                                               float* __restrict__ dout) {
  const int idx = blockIdx.x * 256 + threadIdx.x;  // < 8*3*16384
  const int px = idx & 16383;
  const int t = idx >> 14;
  const int o = t % 3, b = t / 3;
  const float* src = outbuf + (size_t)b * F0_ * 16384 + px;
  const float* wr = out_w + o * F0_;
  float acc = out_b[o];
#pragma unroll 8
  for (int i = 0; i < F0_; ++i) acc = fmaf(wr[i], src[(size_t)i * 16384], acc);
  dout[idx] = fminf(fmaxf(acc, -1.f), 1.f);
  dout[393216 + idx] = acc;
}

// ---------------- host launch ----------------
extern "C" void kernel_launch(void* const* d_in, const int* in_sizes, int n_in,
                              void* d_out, int out_size, void* d_ws, size_t ws_size,
                              hipStream_t stream) {
  const float* lat       = (const float*)d_in[0];
  const float* seed      = (const float*)d_in[1];
  const float* leak      = (const float*)d_in[2];
  const float* lat_exp_w = (const float*)d_in[3];
  const float* lat_exp_b = (const float*)d_in[4];
  const float* noise_w   = (const float*)d_in[5];
  const float* dyna_w    = (const float*)d_in[6];
  const float* dyna_b    = (const float*)d_in[7];
  const float* conv0_w   = (const float*)d_in[8];
  const float* conv0_b   = (const float*)d_in[9];
  const float* conv1_w   = (const float*)d_in[10];
  const float* conv1_b   = (const float*)d_in[11];
  const float* convs_w   = (const float*)d_in[12];
  const float* out_w     = (const float*)d_in[13];
  const float* out_b     = (const float*)d_in[14];

  float* wsf   = (float*)d_ws;   // needs ~158 MB; assume ws_size suffices
  float* latc  = wsf + OFF_LATC;
  float* ksbuf = wsf + OFF_KS;
  float* outb  = wsf + OFF_OUT;
  float* pbuf  = wsf + OFF_P;
  float* tmpb  = wsf + OFF_TMP;

  // per-layer folded threefry keys: fold_in(key(7), c) = cipher(k=(0,7), x=(0,c))
  uint32_t lk0[NLAY_], lk1[NLAY_];
  for (int c = 0; c < NLAY_; ++c)
    host_tf_cipher(0u, 7u, 0u, (uint32_t)c, lk0[c], lk1[c]);

  // gaussian taps (match numpy float64 -> float32 cast)
  const double ga = exp(-0.5);
  const double tot = (1.0 + 2.0 * ga) * (1.0 + 2.0 * ga);
  const float wc = (float)(ga * ga / tot);
  const float we = (float)(ga / tot);
  const float wm = (float)(1.0 / tot);

  k_seed<<<(B_ * F0_ * 256) / 256, 256, 0, stream>>>(seed, outb);
  k_latc<<<NLAY_, 256, 0, stream>>>(lat, lat_exp_w, lat_exp_b, latc);
  k_ks<<<P_ / 64, 256, 0, stream>>>(latc, dyna_w, dyna_b, ksbuf);

  int H = 16, W = 16, logW = 4;
  for (int c = 0; c < NLAY_; ++c) {
    const int HW = H * W;
    k_prep<<<B_ * F0_, 256, 0, stream>>>(outb, pbuf, H, W, logW);
    k_main<<<dim3(HW / 64, B_), 256, 0, stream>>>(
        pbuf, outb, ksbuf + (size_t)c * B_ * P_,
        conv0_w, conv0_b, conv1_w, conv1_b, convs_w,
        noise_w + c * F0_, leak, HW, lk0[c], lk1[c]);
    if ((c & 3) == 3 && c < NLAY_ - 1) {
      const int n1 = B_ * F0_ * 4 * H * W;
      k_resize<<<(n1 + 255) / 256, 256, 0, stream>>>(outb, tmpb, H, W);
      H *= 2; W *= 2; logW += 1;
      k_gauss<<<(n1 + 255) / 256, 256, 0, stream>>>(tmpb, outb, H, W, wc, we, wm);
    }
  }
  k_final<<<(B_ * 3 * 16384) / 256, 256, 0, stream>>>(outb, out_w, out_b,
                                                      (float*)d_out);
  (void)in_sizes; (void)n_in; (void)out_size; (void)ws_size;
}

// Round 2
// 1692.335 us; speedup vs baseline: 1.5439x; 1.5439x over previous
//
#include <hip/hip_runtime.h>
#include <cstdint>
#include <cstddef>
#include <cmath>

#define DI __device__ __forceinline__

#define NOISE_PARTITIONABLE 1

constexpr int B_ = 8;
constexpr int F0_ = 64;
constexpr int FIN_ = 192;
constexpr int LAT_ = 512;
constexpr int P_ = 45376;
constexpr int NLAY_ = 16;

typedef __attribute__((ext_vector_type(8))) short short8;
typedef __attribute__((ext_vector_type(4))) float f32x4;

// ---- workspace layout ----
// floats:
constexpr size_t OFF_LATC = 0;                 // 65536 f
constexpr size_t OFF_OUT  = 65536;             // 8388608 f
constexpr size_t OFF_MS   = 8454144;           // 1536 f
constexpr size_t OFF_RS   = 8455680;           // 1536 f
constexpr size_t OFF_B3   = 8457216;           // 128*320 f
// bytes:
constexpr size_t BOFF_PRAW = 33992704;         // 25165824 u16
constexpr size_t BOFF_PLRE = 84324352;         // 25165824 u16
constexpr size_t BOFF_WPK  = 134656000;        // 128*65536 u16  (end 151.4MB)

// wpk per-(c,b) slot: [128][192] W1 | [128][192] WS | [128][128] W2  (bf16)
constexpr int WPK_STRIDE = 65536;
constexpr int WPK_WS = 24576;
constexpr int WPK_W2 = 49152;
// bias3 per-(c,b): [64] b0 | [128] b1 | [128] bs (f32)

DI uint16_t f2bf(float f) {
  uint32_t u = __float_as_uint(f);
  uint32_t r = (u + 0x7FFFu + ((u >> 16) & 1u)) >> 16;
  return (uint16_t)r;
}

// ---------------- threefry2x32 ----------------
DI void tf_cipher(uint32_t k0, uint32_t k1, uint32_t x0, uint32_t x1,
                  uint32_t& o0, uint32_t& o1) {
  const uint32_t ks2 = k0 ^ k1 ^ 0x1BD11BDAu;
  uint32_t a = x0 + k0, b = x1 + k1;
#define TFR(r) { a += b; b = (b << (r)) | (b >> (32 - (r))); b ^= a; }
  TFR(13) TFR(15) TFR(26) TFR(6)  a += k1;  b += ks2 + 1u;
  TFR(17) TFR(29) TFR(16) TFR(24) a += ks2; b += k0 + 2u;
  TFR(13) TFR(15) TFR(26) TFR(6)  a += k0;  b += k1 + 3u;
  TFR(17) TFR(29) TFR(16) TFR(24) a += k1;  b += ks2 + 4u;
  TFR(13) TFR(15) TFR(26) TFR(6)  a += ks2; b += k0 + 5u;
#undef TFR
  o0 = a; o1 = b;
}

static void host_tf_cipher(uint32_t k0, uint32_t k1, uint32_t x0, uint32_t x1,
                           uint32_t& o0, uint32_t& o1) {
  const uint32_t ks2 = k0 ^ k1 ^ 0x1BD11BDAu;
  uint32_t a = x0 + k0, b = x1 + k1;
#define TFR(r) { a += b; b = (b << (r)) | (b >> (32 - (r))); b ^= a; }
  TFR(13) TFR(15) TFR(26) TFR(6)  a += k1;  b += ks2 + 1u;
  TFR(17) TFR(29) TFR(16) TFR(24) a += ks2; b += k0 + 2u;
  TFR(13) TFR(15) TFR(26) TFR(6)  a += k0;  b += k1 + 3u;
  TFR(17) TFR(29) TFR(16) TFR(24) a += k1;  b += ks2 + 4u;
  TFR(13) TFR(15) TFR(26) TFR(6)  a += ks2; b += k0 + 5u;
#undef TFR
  o0 = a; o1 = b;
}

DI float erfinv_f(float x) {
  float w = -log1pf(-x * x);
  float p;
  if (w < 5.0f) {
    w = w - 2.5f;
    p = 2.81022636e-08f;
    p = fmaf(p, w, 3.43273939e-07f);
    p = fmaf(p, w, -3.5233877e-06f);
    p = fmaf(p, w, -4.39150654e-06f);
    p = fmaf(p, w, 0.00021858087f);
    p = fmaf(p, w, -0.00125372503f);
    p = fmaf(p, w, -0.00417768164f);
    p = fmaf(p, w, 0.246640727f);
    p = fmaf(p, w, 1.50140941f);
  } else {
    w = sqrtf(w) - 3.0f;
    p = -0.000200214257f;
    p = fmaf(p, w, 0.000100950558f);
    p = fmaf(p, w, 0.00134934322f);
    p = fmaf(p, w, -0.00367342844f);
    p = fmaf(p, w, 0.00573950773f);
    p = fmaf(p, w, -0.0076224613f);
    p = fmaf(p, w, 0.00943887047f);
    p = fmaf(p, w, 1.00167406f);
    p = fmaf(p, w, 2.83297682f);
  }
  return p * x;
}

DI float noise_val(uint32_t k0, uint32_t k1, uint32_t idx) {
  uint32_t o0, o1, bits;
  tf_cipher(k0, k1, 0u, idx, o0, o1);
  bits = o0 ^ o1;
  float f = __uint_as_float((bits >> 9) | 0x3f800000u) - 1.0f;
  const float lo = -0.99999994f;
  float u = fmaxf(lo, fmaf(f, 2.0f, lo));
  return 1.41421354f * erfinv_f(u);
}

// ---------------- seed broadcast ----------------
__global__ __launch_bounds__(256) void k_seed(const float* __restrict__ seed,
                                              float* __restrict__ outb) {
  int idx = blockIdx.x * 256 + threadIdx.x;
  outb[idx] = seed[idx & (F0_ * 256 - 1)];
}

// ---------------- latc ----------------
__global__ __launch_bounds__(256) void k_latc(const float* __restrict__ lat,
                                              const float* __restrict__ wexp,
                                              const float* __restrict__ bexp,
                                              float* __restrict__ latc) {
  const int c = blockIdx.x;
  const int tid = threadIdx.x;
  __shared__ float latS[B_][LAT_];
  for (int i = tid; i < B_ * LAT_; i += 256) latS[i >> 9][i & 511] = lat[i];
  __syncthreads();
  for (int o = tid; o < LAT_; o += 256) {
    float acc[B_] = {0, 0, 0, 0, 0, 0, 0, 0};
    const float* wr = wexp + ((size_t)c * LAT_ + o) * LAT_;
    for (int k = 0; k < LAT_; k += 4) {
      float4 w4 = *(const float4*)(wr + k);
#pragma unroll
      for (int b = 0; b < B_; ++b) {
        acc[b] = fmaf(w4.x, latS[b][k + 0], acc[b]);
        acc[b] = fmaf(w4.y, latS[b][k + 1], acc[b]);
        acc[b] = fmaf(w4.z, latS[b][k + 2], acc[b]);
        acc[b] = fmaf(w4.w, latS[b][k + 3], acc[b]);
      }
    }
    const float bb = bexp[c * LAT_ + o];
#pragma unroll
    for (int b = 0; b < B_; ++b)
      latc[((size_t)c * B_ + b) * LAT_ + o] = acc[b] + bb;
  }
}

// ---------------- static weight fill ----------------
__global__ __launch_bounds__(256) void k_wstatic(const float* __restrict__ conv0_w,
                                                 const float* __restrict__ conv1_w,
                                                 unsigned short* __restrict__ wpk) {
  const int cb = blockIdx.x;
  unsigned short* wq = wpk + (size_t)cb * WPK_STRIDE;
  for (int i = threadIdx.x; i < 64 * 192; i += 256) wq[i] = f2bf(conv0_w[i]);
  for (int i = threadIdx.x; i < 128 * 64; i += 256) {
    int oc = i >> 6, k = i & 63;
    wq[WPK_W2 + oc * 128 + k] = f2bf(0.1f * conv1_w[i]);
  }
}

// ---------------- ks GEMM -> packed bf16 weights + f32 biases ----------------
__global__ __launch_bounds__(256) void k_ks(const float* __restrict__ latc,
                                            const float* __restrict__ dyna_w,
                                            const float* __restrict__ dyna_b,
                                            const float* __restrict__ convs_w,
                                            unsigned short* __restrict__ wpk,
                                            float* __restrict__ bias3) {
  const int n0 = blockIdx.x * 64;
  const int tid = threadIdx.x;
  const int tx = tid & 15, ty = tid >> 4;
  __shared__ __align__(16) float As[16][128];
  __shared__ __align__(16) float Bs[16][64];
  float acc[8][4];
#pragma unroll
  for (int i = 0; i < 8; ++i)
#pragma unroll
    for (int j = 0; j < 4; ++j) acc[i][j] = 0.f;

  const int m_f = tid >> 1, kq_f = tid & 1;
  const int n_f = tid >> 2, kq4_f = tid & 3;

  for (int kc = 0; kc < LAT_; kc += 16) {
    __syncthreads();
    {
      const float* src = latc + (size_t)m_f * LAT_ + kc + kq_f * 8;
      float4 a0 = *(const float4*)(src);
      float4 a1 = *(const float4*)(src + 4);
      int kb = kq_f * 8;
      As[kb + 0][m_f] = a0.x; As[kb + 1][m_f] = a0.y; As[kb + 2][m_f] = a0.z; As[kb + 3][m_f] = a0.w;
      As[kb + 4][m_f] = a1.x; As[kb + 5][m_f] = a1.y; As[kb + 6][m_f] = a1.z; As[kb + 7][m_f] = a1.w;
    }
    {
      const float4 v = *(const float4*)(dyna_w + (size_t)(n0 + n_f) * LAT_ + kc + kq4_f * 4);
      int kb = kq4_f * 4;
      Bs[kb + 0][n_f] = v.x; Bs[kb + 1][n_f] = v.y; Bs[kb + 2][n_f] = v.z; Bs[kb + 3][n_f] = v.w;
    }
    __syncthreads();
#pragma unroll
    for (int k = 0; k < 16; ++k) {
      const float4 xv = *(const float4*)&Bs[k][tx * 4];
      const float4 wa = *(const float4*)&As[k][ty * 8];
      const float4 wb = *(const float4*)&As[k][ty * 8 + 4];
      const float wv[8] = {wa.x, wa.y, wa.z, wa.w, wb.x, wb.y, wb.z, wb.w};
#pragma unroll
      for (int i = 0; i < 8; ++i) {
        acc[i][0] = fmaf(wv[i], xv.x, acc[i][0]);
        acc[i][1] = fmaf(wv[i], xv.y, acc[i][1]);
        acc[i][2] = fmaf(wv[i], xv.z, acc[i][2]);
        acc[i][3] = fmaf(wv[i], xv.w, acc[i][3]);
      }
    }
  }

  // epilogue: route to packed destinations (boundaries all %64 -> uniform per block)
  const int nn = n0 + tx * 4;
  const float4 db4 = *(const float4*)(dyna_b + nn);
  int typ, e_off;
  float s0 = 0.f, s1 = 0.f, s2 = 0.f, s3 = 0.f;
  if (nn < 12288) { int q = nn / 192, r2 = nn - q * 192; typ = 0; e_off = (64 + q) * 192 + r2; }
  else if (nn < 12352) { typ = 1; e_off = nn - 12288; }
  else if (nn < 20544) { int m2 = nn - 12352; int oc = m2 >> 6, k = m2 & 63; typ = 2; e_off = WPK_W2 + oc * 128 + 64 + k; }
  else if (nn < 20672) { typ = 3; e_off = 64 + (nn - 20544); }
  else if (nn < 45248) {
    int m3 = nn - 20672; int oc = m3 / 192, k = m3 - oc * 192; typ = 4; e_off = WPK_WS + oc * 192 + k;
    float4 cs = *(const float4*)(convs_w + oc * 192 + k);
    s0 = cs.x; s1 = cs.y; s2 = cs.z; s3 = cs.w;
  } else { typ = 5; e_off = 192 + (nn - 45248); }

#pragma unroll
  for (int i = 0; i < 8; ++i) {
    const int cb = ty * 8 + i;
    float v0 = acc[i][0] + db4.x, v1 = acc[i][1] + db4.y;
    float v2 = acc[i][2] + db4.z, v3 = acc[i][3] + db4.w;
    if (typ == 4) { v0 += s0; v1 += s1; v2 += s2; v3 += s3; }
    if (typ == 2) { v0 *= 0.1f; v1 *= 0.1f; v2 *= 0.1f; v3 *= 0.1f; }
    if (typ == 0 || typ == 2 || typ == 4) {
      unsigned short* dst = wpk + (size_t)cb * WPK_STRIDE + e_off;
      uint2 u;
      u.x = (unsigned)f2bf(v0) | ((unsigned)f2bf(v1) << 16);
      u.y = (unsigned)f2bf(v2) | ((unsigned)f2bf(v3) << 16);
      *(uint2*)dst = u;
    } else {
      float* dst = bias3 + (size_t)cb * 320 + e_off;
      *(float4*)dst = make_float4(v0, v1, v2, v3);
    }
  }
}

// ---------------- sobel helper ----------------
DI void conv9(const float* __restrict__ pl, int h, int w, int H, int W,
              float& vx, float& vy, float& vi) {
  const bool up = h > 0, dn = h < H - 1, lf = w > 0, rt = w < W - 1;
  const float* r0 = pl + (size_t)(h - 1) * W;
  const float* r1 = pl + (size_t)h * W;
  const float* r2 = pl + (size_t)(h + 1) * W;
  float c00 = (up && lf) ? r0[w - 1] : 0.f;
  float c01 = up ? r0[w] : 0.f;
  float c02 = (up && rt) ? r0[w + 1] : 0.f;
  float c10 = lf ? r1[w - 1] : 0.f;
  float c11v = r1[w];
  float c12 = rt ? r1[w + 1] : 0.f;
  float c20 = (dn && lf) ? r2[w - 1] : 0.f;
  float c21 = dn ? r2[w] : 0.f;
  float c22 = (dn && rt) ? r2[w + 1] : 0.f;
  vx = (c02 - c00 + 2.f * (c12 - c10) + (c22 - c20)) * 0.125f;
  vy = (c20 - c00 + 2.f * (c21 - c01) + (c22 - c02)) * 0.125f;
  vi = c11v;
}

// ---------------- stats (mean/rstd of vx,vy,vi per (b,ch)) ----------------
__global__ __launch_bounds__(256) void k_stats(const float* __restrict__ outb,
                                               float* __restrict__ m_s,
                                               float* __restrict__ r_s,
                                               int H, int W, int logW) {
  const int bc = blockIdx.x;
  const int b = bc >> 6, ch = bc & 63;
  const int HW = H * W;
  const float* __restrict__ pl = outb + (size_t)(b * F0_ + ch) * HW;
  const int tid = threadIdx.x;

  float s[6] = {0, 0, 0, 0, 0, 0};
  for (int px = tid; px < HW; px += 256) {
    const int h = px >> logW, w = px & (W - 1);
    float vx, vy, vi;
    conv9(pl, h, w, H, W, vx, vy, vi);
    s[0] += vx; s[1] += vx * vx;
    s[2] += vy; s[3] += vy * vy;
    s[4] += vi; s[5] += vi * vi;
  }
  __shared__ float red[4][6];
#pragma unroll
  for (int i = 0; i < 6; ++i)
#pragma unroll
    for (int off = 32; off > 0; off >>= 1)
      s[i] += __shfl_down(s[i], off, 64);
  const int lane = tid & 63, wv = tid >> 6;
  if (lane == 0) {
#pragma unroll
    for (int i = 0; i < 6; ++i) red[wv][i] = s[i];
  }
  __syncthreads();
  if (tid == 0) {
    float fin[6];
#pragma unroll
    for (int i = 0; i < 6; ++i)
      fin[i] = red[0][i] + red[1][i] + red[2][i] + red[3][i];
    const float inv = 1.0f / (float)HW;
    const float mx = fin[0] * inv, my = fin[2] * inv, mi = fin[4] * inv;
    m_s[b * 192 + ch] = mx;
    m_s[b * 192 + 64 + ch] = my;
    m_s[b * 192 + 128 + ch] = mi;
    r_s[b * 192 + ch] = rsqrtf(fmaxf(fin[1] * inv - mx * mx, 0.f) + 1e-5f);
    r_s[b * 192 + 64 + ch] = rsqrtf(fmaxf(fin[3] * inv - my * my, 0.f) + 1e-5f);
    r_s[b * 192 + 128 + ch] = rsqrtf(fmaxf(fin[5] * inv - mi * mi, 0.f) + 1e-5f);
  }
}

// ---------------- p writer: px-major bf16 (raw + lrelu) ----------------
__global__ __launch_bounds__(256) void k_pwrite(const float* __restrict__ outb,
                                                const float* __restrict__ m_s,
                                                const float* __restrict__ r_s,
                                                unsigned short* __restrict__ p_raw,
                                                unsigned short* __restrict__ p_lre,
                                                int H, int W) {
  const int b = blockIdx.y;
  const int r0 = blockIdx.x * 2;
  const int HW = H * W;
  const int tid = threadIdx.x;
  const int chl = tid & 15, pxg = tid >> 4;
  const int Wp = W + 2;
  __shared__ float ldsIn[4 * 130 * 17];

  for (int cc = 0; cc < 4; ++cc) {
    __syncthreads();
    const int tot = 16 * 4 * Wp;
    for (int i = tid; i < tot; i += 256) {
      const int ch = i / (4 * Wp);
      const int rem = i - ch * (4 * Wp);
      const int rr = rem / Wp;
      const int wl = rem - rr * Wp;
      const int gr = r0 - 1 + rr;
      float v = 0.f;
      if (gr >= 0 && gr < H && wl >= 1 && wl <= W)
        v = outb[((size_t)(b * F0_ + cc * 16 + ch)) * HW + (size_t)gr * W + (wl - 1)];
      ldsIn[(rr * Wp + wl) * 17 + ch] = v;
    }
    __syncthreads();
    const int ch = cc * 16 + chl;
    const float mx = m_s[b * 192 + ch],       rx = r_s[b * 192 + ch];
    const float my = m_s[b * 192 + 64 + ch],  ry = r_s[b * 192 + 64 + ch];
    const float mi = m_s[b * 192 + 128 + ch], ri = r_s[b * 192 + 128 + ch];
    const int np = (2 * W) / 16;
    for (int it = 0; it < np; ++it) {
      const int px = it * 16 + pxg;
      const int rl = (px >= W) ? 1 : 0;
      const int w = px - rl * W;
      const float c00 = ldsIn[((rl + 0) * Wp + w + 0) * 17 + chl];
      const float c01 = ldsIn[((rl + 0) * Wp + w + 1) * 17 + chl];
      const float c02 = ldsIn[((rl + 0) * Wp + w + 2) * 17 + chl];
      const float c10 = ldsIn[((rl + 1) * Wp + w + 0) * 17 + chl];
      const float c11 = ldsIn[((rl + 1) * Wp + w + 1) * 17 + chl];
      const float c12 = ldsIn[((rl + 1) * Wp + w + 2) * 17 + chl];
      const float c20 = ldsIn[((rl + 2) * Wp + w + 0) * 17 + chl];
      const float c21 = ldsIn[((rl + 2) * Wp + w + 1) * 17 + chl];
      const float c22 = ldsIn[((rl + 2) * Wp + w + 2) * 17 + chl];
      const float vx = (c02 - c00 + 2.f * (c12 - c10) + (c22 - c20)) * 0.125f;
      const float vy = (c20 - c00 + 2.f * (c21 - c01) + (c22 - c02)) * 0.125f;
      const float nx = (vx - mx) * rx;
      const float ny = (vy - my) * ry;
      const float ni = (c11 - mi) * ri;
      const size_t prow = ((size_t)b * HW + (size_t)r0 * W + px) * 192;
      p_raw[prow + ch] = f2bf(nx);
      p_raw[prow + 64 + ch] = f2bf(ny);
      p_raw[prow + 128 + ch] = f2bf(ni);
      p_lre[prow + ch] = f2bf(nx > 0.f ? nx : 0.2f * nx);
      p_lre[prow + 64 + ch] = f2bf(ny > 0.f ? ny : 0.2f * ny);
      p_lre[prow + 128 + ch] = f2bf(ni > 0.f ? ni : 0.2f * ni);
    }
  }
}

// ---------------- fused MFMA main layer kernel ----------------
__global__ __launch_bounds__(256) void k_main(
    const unsigned short* __restrict__ p_raw,
    const unsigned short* __restrict__ p_lre,
    float* __restrict__ out,
    const unsigned short* __restrict__ wpk_layer,
    const float* __restrict__ bias3_layer,
    const float* __restrict__ conv0_b,
    const float* __restrict__ conv1_b,
    const float* __restrict__ noise_w_c,
    const float* __restrict__ leak_ptr,
    int HW, unsigned key0, unsigned key1) {
  const int b = blockIdx.y;
  const int gp0 = blockIdx.x * 64;
  const int tid = threadIdx.x;
  const int wv = tid >> 6, lane = tid & 63;
  const int lg = lane >> 4, lr = lane & 15;

  __shared__ __align__(16) unsigned short Hs[64 * 136];
  __shared__ float noiseS[64];

  const unsigned short* wq = wpk_layer + (size_t)b * WPK_STRIDE;
  const unsigned short* W1 = wq;
  const unsigned short* WS = wq + WPK_WS;
  const unsigned short* W2 = wq + WPK_W2;
  const float* b3 = bias3_layer + (size_t)b * 320;

  const size_t prow_base = ((size_t)b * HW + gp0) * 192;
  const int oc0 = 16 * wv;
  const int oc1 = 64 + 16 * wv;

  f32x4 accH[2][4], accO[2][4];
#pragma unroll
  for (int t = 0; t < 2; ++t)
#pragma unroll
    for (int p = 0; p < 4; ++p) { accH[t][p] = (f32x4)0.f; accO[t][p] = (f32x4)0.f; }

  // GEMM1 (W1 @ lrelu(p)) and GEMM2A (WS @ p), K=192
#pragma unroll
  for (int kc = 0; kc < 6; ++kc) {
    const int ko = kc * 32 + lg * 8;
    const short8 a10 = *(const short8*)(W1 + (size_t)(oc0 + lr) * 192 + ko);
    const short8 a11 = *(const short8*)(W1 + (size_t)(oc1 + lr) * 192 + ko);
    const short8 as0 = *(const short8*)(WS + (size_t)(oc0 + lr) * 192 + ko);
    const short8 as1 = *(const short8*)(WS + (size_t)(oc1 + lr) * 192 + ko);
#pragma unroll
    for (int pxt = 0; pxt < 4; ++pxt) {
      const size_t pr = prow_base + (size_t)(pxt * 16 + lr) * 192 + ko;
      const short8 bl = *(const short8*)(p_lre + pr);
      const short8 br = *(const short8*)(p_raw + pr);
      accH[0][pxt] = __builtin_amdgcn_mfma_f32_16x16x32_bf16(a10, bl, accH[0][pxt], 0, 0, 0);
      accH[1][pxt] = __builtin_amdgcn_mfma_f32_16x16x32_bf16(a11, bl, accH[1][pxt], 0, 0, 0);
      accO[0][pxt] = __builtin_amdgcn_mfma_f32_16x16x32_bf16(as0, br, accO[0][pxt], 0, 0, 0);
      accO[1][pxt] = __builtin_amdgcn_mfma_f32_16x16x32_bf16(as1, br, accO[1][pxt], 0, 0, 0);
    }
  }

  // h = lrelu(acc + bias) -> LDS (bf16, [px][136])
#pragma unroll
  for (int ti = 0; ti < 2; ++ti) {
    const int ocb = ti ? oc1 : oc0;
    float bh[4];
#pragma unroll
    for (int r = 0; r < 4; ++r) {
      const int oc = ocb + lg * 4 + r;
      bh[r] = (oc < 64) ? conv0_b[oc] : b3[oc - 64];
    }
#pragma unroll
    for (int pxt = 0; pxt < 4; ++pxt) {
      const int px = pxt * 16 + lr;
#pragma unroll
      for (int rp = 0; rp < 2; ++rp) {
        float h0 = accH[ti][pxt][rp * 2 + 0] + bh[rp * 2 + 0];
        float h1 = accH[ti][pxt][rp * 2 + 1] + bh[rp * 2 + 1];
        h0 = h0 > 0.f ? h0 : 0.2f * h0;
        h1 = h1 > 0.f ? h1 : 0.2f * h1;
        const unsigned u = (unsigned)f2bf(h0) | ((unsigned)f2bf(h1) << 16);
        *(unsigned*)(&Hs[(size_t)px * 136 + ocb + lg * 4 + rp * 2]) = u;
      }
    }
  }
  if (tid < 64)
    noiseS[tid] = noise_val(key0, key1, (unsigned)(b * HW + gp0 + tid));
  __syncthreads();

  // GEMM2B: += W2 @ lrelu(h), K=128
#pragma unroll
  for (int kc = 0; kc < 4; ++kc) {
    const int ko = kc * 32 + lg * 8;
    const short8 a20 = *(const short8*)(W2 + (size_t)(oc0 + lr) * 128 + ko);
    const short8 a21 = *(const short8*)(W2 + (size_t)(oc1 + lr) * 128 + ko);
#pragma unroll
    for (int pxt = 0; pxt < 4; ++pxt) {
      const short8 hb = *(const short8*)(&Hs[(size_t)(pxt * 16 + lr) * 136 + ko]);
      accO[0][pxt] = __builtin_amdgcn_mfma_f32_16x16x32_bf16(a20, hb, accO[0][pxt], 0, 0, 0);
      accO[1][pxt] = __builtin_amdgcn_mfma_f32_16x16x32_bf16(a21, hb, accO[1][pxt], 0, 0, 0);
    }
  }

  // epilogue: bias, GLU, noise, out +=
  const float lfv = fminf(fmaxf(leak_ptr[0], 0.001f), 1000.0f);
  float boA[4], boG[4], nw[4];
#pragma unroll
  for (int r = 0; r < 4; ++r) {
    const int oca = oc0 + lg * 4 + r;
    const int ocg = oc1 + lg * 4 + r;
    boA[r] = b3[192 + oca] + 0.1f * (conv1_b[oca] + b3[64 + oca]);
    boG[r] = b3[192 + ocg] + 0.1f * (conv1_b[ocg] + b3[64 + ocg]);
    nw[r] = noise_w_c[oca];
  }
#pragma unroll
  for (int pxt = 0; pxt < 4; ++pxt) {
    const int px = pxt * 16 + lr;
    const float nz = noiseS[px];
#pragma unroll
    for (int r = 0; r < 4; ++r) {
      const float a = accO[0][pxt][r] + boA[r];
      const float g = accO[1][pxt][r] + boG[r];
      const float og = a * (1.0f / (1.0f + expf(-g)));
      const float val = og + nw[r] * nz;
      const int ch = oc0 + lg * 4 + r;
      float* op = out + (size_t)(b * F0_ + ch) * HW + gp0 + px;
      *op += lfv * val;
    }
  }
}

// ---------------- bilinear 2x resize ----------------
__global__ __launch_bounds__(256) void k_resize(const float* __restrict__ src,
                                                float* __restrict__ dst,
                                                int H, int W) {
  const int OW = 2 * W;
  const int OHW = 4 * H * W;
  const int idx = blockIdx.x * 256 + threadIdx.x;
  if (idx >= B_ * F0_ * OHW) return;
  const int plane = idx / OHW;
  const int opx = idx - plane * OHW;
  const int oh = opx / OW, ow = opx - oh * OW;
  const float shf = 0.5f * oh - 0.25f;
  const float swf = 0.5f * ow - 0.25f;
  int h0 = (int)floorf(shf); const float fh = shf - h0;
  int w0 = (int)floorf(swf); const float fw = swf - w0;
  int h1 = min(h0 + 1, H - 1); h0 = max(h0, 0);
  int w1 = min(w0 + 1, W - 1); w0 = max(w0, 0);
  const float* pl = src + (size_t)plane * H * W;
  const float v00 = pl[h0 * W + w0], v01 = pl[h0 * W + w1];
  const float v10 = pl[h1 * W + w0], v11 = pl[h1 * W + w1];
  dst[idx] = (1.f - fh) * ((1.f - fw) * v00 + fw * v01) +
             fh * ((1.f - fw) * v10 + fw * v11);
}

// ---------------- gaussian 3x3 depthwise ----------------
__global__ __launch_bounds__(256) void k_gauss(const float* __restrict__ src,
                                               float* __restrict__ dst,
                                               int H, int W,
                                               float wc, float we, float wm) {
  const int HW = H * W;
  const int idx = blockIdx.x * 256 + threadIdx.x;
  if (idx >= B_ * F0_ * HW) return;
  const int plane = idx / HW;
  const int px = idx - plane * HW;
  const int h = px / W, w = px - h * W;
  const float* pl = src + (size_t)plane * HW;
  const bool up = h > 0, dn = h < H - 1, lf = w > 0, rt = w < W - 1;
  const float* r0 = pl + (size_t)(h - 1) * W;
  const float* r1 = pl + (size_t)h * W;
  const float* r2 = pl + (size_t)(h + 1) * W;
  const float c00 = (up && lf) ? r0[w - 1] : 0.f;
  const float c01 = up ? r0[w] : 0.f;
  const float c02 = (up && rt) ? r0[w + 1] : 0.f;
  const float c10 = lf ? r1[w - 1] : 0.f;
  const float c11v = r1[w];
  const float c12 = rt ? r1[w + 1] : 0.f;
  const float c20 = (dn && lf) ? r2[w - 1] : 0.f;
  const float c21 = dn ? r2[w] : 0.f;
  const float c22 = (dn && rt) ? r2[w + 1] : 0.f;
  dst[idx] = wc * (c00 + c02 + c20 + c22) + we * (c01 + c10 + c12 + c21) + wm * c11v;
}

// ---------------- final 1x1 conv + clip ----------------
__global__ __launch_bounds__(256) void k_final(const float* __restrict__ outbuf,
                                               const float* __restrict__ out_w,
                                               const float* __restrict__ out_b,
                                               float* __restrict__ dout) {
  const int idx = blockIdx.x * 256 + threadIdx.x;
  const int px = idx & 16383;
  const int t = idx >> 14;
  const int o = t % 3, b = t / 3;
  const float* src = outbuf + (size_t)b * F0_ * 16384 + px;
  const float* wr = out_w + o * F0_;
  float acc = out_b[o];
#pragma unroll 8
  for (int i = 0; i < F0_; ++i) acc = fmaf(wr[i], src[(size_t)i * 16384], acc);
  dout[idx] = fminf(fmaxf(acc, -1.f), 1.f);
  dout[393216 + idx] = acc;
}

// ---------------- host launch ----------------
extern "C" void kernel_launch(void* const* d_in, const int* in_sizes, int n_in,
                              void* d_out, int out_size, void* d_ws, size_t ws_size,
                              hipStream_t stream) {
  const float* lat       = (const float*)d_in[0];
  const float* seed      = (const float*)d_in[1];
  const float* leak      = (const float*)d_in[2];
  const float* lat_exp_w = (const float*)d_in[3];
  const float* lat_exp_b = (const float*)d_in[4];
  const float* noise_w   = (const float*)d_in[5];
  const float* dyna_w    = (const float*)d_in[6];
  const float* dyna_b    = (const float*)d_in[7];
  const float* conv0_w   = (const float*)d_in[8];
  const float* conv0_b   = (const float*)d_in[9];
  const float* conv1_w   = (const float*)d_in[10];
  const float* conv1_b   = (const float*)d_in[11];
  const float* convs_w   = (const float*)d_in[12];
  const float* out_w     = (const float*)d_in[13];
  const float* out_b     = (const float*)d_in[14];

  float* wsf = (float*)d_ws;
  float* latc = wsf + OFF_LATC;
  float* outb = wsf + OFF_OUT;
  float* m_s  = wsf + OFF_MS;
  float* r_s  = wsf + OFF_RS;
  float* b3   = wsf + OFF_B3;
  unsigned short* p_raw = (unsigned short*)((char*)d_ws + BOFF_PRAW);
  unsigned short* p_lre = (unsigned short*)((char*)d_ws + BOFF_PLRE);
  unsigned short* wpk   = (unsigned short*)((char*)d_ws + BOFF_WPK);
  float* tmpb = (float*)p_raw;  // resize scratch aliases p (dead at resize time)

  uint32_t lk0[NLAY_], lk1[NLAY_];
  for (int c = 0; c < NLAY_; ++c)
    host_tf_cipher(0u, 7u, 0u, (uint32_t)c, lk0[c], lk1[c]);

  const double ga = exp(-0.5);
  const double tot = (1.0 + 2.0 * ga) * (1.0 + 2.0 * ga);
  const float wc = (float)(ga * ga / tot);
  const float we = (float)(ga / tot);
  const float wm = (float)(1.0 / tot);

  k_seed<<<(B_ * F0_ * 256) / 256, 256, 0, stream>>>(seed, outb);
  k_latc<<<NLAY_, 256, 0, stream>>>(lat, lat_exp_w, lat_exp_b, latc);
  k_wstatic<<<NLAY_ * B_, 256, 0, stream>>>(conv0_w, conv1_w, wpk);
  k_ks<<<P_ / 64, 256, 0, stream>>>(latc, dyna_w, dyna_b, convs_w, wpk, b3);

  int H = 16, W = 16, logW = 4;
  for (int c = 0; c < NLAY_; ++c) {
    const int HW = H * W;
    k_stats<<<B_ * F0_, 256, 0, stream>>>(outb, m_s, r_s, H, W, logW);
    k_pwrite<<<dim3(H / 2, B_), 256, 0, stream>>>(outb, m_s, r_s, p_raw, p_lre, H, W);
    k_main<<<dim3(HW / 64, B_), 256, 0, stream>>>(
        p_raw, p_lre, outb,
        wpk + (size_t)c * B_ * WPK_STRIDE, b3 + (size_t)c * B_ * 320,
        conv0_b, conv1_b, noise_w + c * F0_, leak, HW, lk0[c], lk1[c]);
    if ((c & 3) == 3 && c < NLAY_ - 1) {
      const int n1 = B_ * F0_ * 4 * H * W;
      k_resize<<<(n1 + 255) / 256, 256, 0, stream>>>(outb, tmpb, H, W);
      H *= 2; W *= 2; logW += 1;
      k_gauss<<<(n1 + 255) / 256, 256, 0, stream>>>(tmpb, outb, H, W, wc, we, wm);
    }
  }
  k_final<<<(B_ * 3 * 16384) / 256, 256, 0, stream>>>(outb, out_w, out_b,
                                                      (float*)d_out);
  (void)in_sizes; (void)n_in; (void)out_size; (void)ws_size;
}

// Round 3
// 1117.418 us; speedup vs baseline: 2.3382x; 1.5145x over previous
//
#include <hip/hip_runtime.h>
#include <cstdint>
#include <cstddef>
#include <cmath>

#define DI __device__ __forceinline__

constexpr int B_ = 8;
constexpr int F0_ = 64;
constexpr int LAT_ = 512;
constexpr int P_ = 45376;
constexpr int NLAY_ = 16;

typedef __attribute__((ext_vector_type(8))) short short8;
typedef __attribute__((ext_vector_type(4))) float f32x4;

// wpk per-(c,b) slot: [128][192] W1 | [128][192] WS | [128][128] W2  (bf16)
constexpr int WPK_STRIDE = 65536;
constexpr int WPK_WS = 24576;
constexpr int WPK_W2 = 49152;

// ---- workspace layout (float offsets) ----
constexpr size_t OFF_LATC   = 0;          // 128*512 f32
constexpr size_t OFF_MS     = 65536;      // 1536
constexpr size_t OFF_RS     = 67072;      // 1536
constexpr size_t OFF_B3     = 68608;      // 128*320
constexpr size_t OFF_LATCBF = 109568;     // 128*512 u16 = 32768 f-slots
constexpr size_t OFF_OUT0   = 142336;     // 8*64*16384
constexpr size_t OFF_OUT1   = 8530944;
constexpr size_t OFF_WPK    = 16919552;   // 128*65536 u16 = 4194304 f-slots -> end 21113856 f (84.5MB)

DI uint16_t f2bf(float f) {
  uint32_t u = __float_as_uint(f);
  uint32_t r = (u + 0x7FFFu + ((u >> 16) & 1u)) >> 16;
  return (uint16_t)r;
}
DI uint32_t pk2bf(float a, float b) {
  return (uint32_t)f2bf(a) | ((uint32_t)f2bf(b) << 16);
}

// ---------------- threefry2x32 ----------------
DI void tf_cipher(uint32_t k0, uint32_t k1, uint32_t x0, uint32_t x1,
                  uint32_t& o0, uint32_t& o1) {
  const uint32_t ks2 = k0 ^ k1 ^ 0x1BD11BDAu;
  uint32_t a = x0 + k0, b = x1 + k1;
#define TFR(r) { a += b; b = (b << (r)) | (b >> (32 - (r))); b ^= a; }
  TFR(13) TFR(15) TFR(26) TFR(6)  a += k1;  b += ks2 + 1u;
  TFR(17) TFR(29) TFR(16) TFR(24) a += ks2; b += k0 + 2u;
  TFR(13) TFR(15) TFR(26) TFR(6)  a += k0;  b += k1 + 3u;
  TFR(17) TFR(29) TFR(16) TFR(24) a += k1;  b += ks2 + 4u;
  TFR(13) TFR(15) TFR(26) TFR(6)  a += ks2; b += k0 + 5u;
#undef TFR
  o0 = a; o1 = b;
}

static void host_tf_cipher(uint32_t k0, uint32_t k1, uint32_t x0, uint32_t x1,
                           uint32_t& o0, uint32_t& o1) {
  const uint32_t ks2 = k0 ^ k1 ^ 0x1BD11BDAu;
  uint32_t a = x0 + k0, b = x1 + k1;
#define TFR(r) { a += b; b = (b << (r)) | (b >> (32 - (r))); b ^= a; }
  TFR(13) TFR(15) TFR(26) TFR(6)  a += k1;  b += ks2 + 1u;
  TFR(17) TFR(29) TFR(16) TFR(24) a += ks2; b += k0 + 2u;
  TFR(13) TFR(15) TFR(26) TFR(6)  a += k0;  b += k1 + 3u;
  TFR(17) TFR(29) TFR(16) TFR(24) a += k1;  b += ks2 + 4u;
  TFR(13) TFR(15) TFR(26) TFR(6)  a += ks2; b += k0 + 5u;
#undef TFR
  o0 = a; o1 = b;
}

DI float erfinv_f(float x) {
  float w = -log1pf(-x * x);
  float p;
  if (w < 5.0f) {
    w = w - 2.5f;
    p = 2.81022636e-08f;
    p = fmaf(p, w, 3.43273939e-07f);
    p = fmaf(p, w, -3.5233877e-06f);
    p = fmaf(p, w, -4.39150654e-06f);
    p = fmaf(p, w, 0.00021858087f);
    p = fmaf(p, w, -0.00125372503f);
    p = fmaf(p, w, -0.00417768164f);
    p = fmaf(p, w, 0.246640727f);
    p = fmaf(p, w, 1.50140941f);
  } else {
    w = sqrtf(w) - 3.0f;
    p = -0.000200214257f;
    p = fmaf(p, w, 0.000100950558f);
    p = fmaf(p, w, 0.00134934322f);
    p = fmaf(p, w, -0.00367342844f);
    p = fmaf(p, w, 0.00573950773f);
    p = fmaf(p, w, -0.0076224613f);
    p = fmaf(p, w, 0.00943887047f);
    p = fmaf(p, w, 1.00167406f);
    p = fmaf(p, w, 2.83297682f);
  }
  return p * x;
}

DI float noise_val(uint32_t k0, uint32_t k1, uint32_t idx) {
  uint32_t o0, o1;
  tf_cipher(k0, k1, 0u, idx, o0, o1);
  uint32_t bits = o0 ^ o1;
  float f = __uint_as_float((bits >> 9) | 0x3f800000u) - 1.0f;
  const float lo = -0.99999994f;
  float u = fmaxf(lo, fmaf(f, 2.0f, lo));
  return 1.41421354f * erfinv_f(u);
}

// ---------------- seed broadcast ----------------
__global__ __launch_bounds__(256) void k_seed(const float* __restrict__ seed,
                                              float* __restrict__ outb) {
  int idx = blockIdx.x * 256 + threadIdx.x;
  outb[idx] = seed[idx & (F0_ * 256 - 1)];
}

// ---------------- latc (f32 + bf16 copy) ----------------
__global__ __launch_bounds__(256) void k_latc(const float* __restrict__ lat,
                                              const float* __restrict__ wexp,
                                              const float* __restrict__ bexp,
                                              float* __restrict__ latc,
                                              unsigned short* __restrict__ latc_bf) {
  const int c = blockIdx.x;
  const int tid = threadIdx.x;
  __shared__ float latS[B_][LAT_];
  for (int i = tid; i < B_ * LAT_; i += 256) latS[i >> 9][i & 511] = lat[i];
  __syncthreads();
  for (int o = tid; o < LAT_; o += 256) {
    float acc[B_] = {0, 0, 0, 0, 0, 0, 0, 0};
    const float* wr = wexp + ((size_t)c * LAT_ + o) * LAT_;
    for (int k = 0; k < LAT_; k += 4) {
      float4 w4 = *(const float4*)(wr + k);
#pragma unroll
      for (int b = 0; b < B_; ++b) {
        acc[b] = fmaf(w4.x, latS[b][k + 0], acc[b]);
        acc[b] = fmaf(w4.y, latS[b][k + 1], acc[b]);
        acc[b] = fmaf(w4.z, latS[b][k + 2], acc[b]);
        acc[b] = fmaf(w4.w, latS[b][k + 3], acc[b]);
      }
    }
    const float bb = bexp[c * LAT_ + o];
#pragma unroll
    for (int b = 0; b < B_; ++b) {
      const float v = acc[b] + bb;
      latc[((size_t)c * B_ + b) * LAT_ + o] = v;
      latc_bf[((size_t)c * B_ + b) * LAT_ + o] = f2bf(v);
    }
  }
}

// ---------------- static weight fill ----------------
__global__ __launch_bounds__(256) void k_wstatic(const float* __restrict__ conv0_w,
                                                 const float* __restrict__ conv1_w,
                                                 unsigned short* __restrict__ wpk) {
  const int cb = blockIdx.x;
  unsigned short* wq = wpk + (size_t)cb * WPK_STRIDE;
  for (int i = threadIdx.x; i < 64 * 192; i += 256) wq[i] = f2bf(conv0_w[i]);
  for (int i = threadIdx.x; i < 128 * 64; i += 256) {
    int oc = i >> 6, k = i & 63;
    wq[WPK_W2 + oc * 128 + k] = f2bf(0.1f * conv1_w[i]);
  }
}

// ---------------- ks via bf16 MFMA: M=128, N=45376, K=512 ----------------
__global__ __launch_bounds__(256) void k_ks(
    const unsigned short* __restrict__ latc_bf,
    const float* __restrict__ dyna_w,
    const float* __restrict__ dyna_b,
    const float* __restrict__ convs_w,
    unsigned short* __restrict__ wpk,
    float* __restrict__ bias3) {
  const int n0 = blockIdx.x * 64;
  const int tid = threadIdx.x;
  const int wv = tid >> 6, lane = tid & 63, lg = lane >> 4, lr = lane & 15;
  __shared__ __align__(16) unsigned char AsB[128 * 64];  // [m][32k] bf16, XOR-swz
  __shared__ __align__(16) unsigned char BsB[64 * 64];   // [n][32k] bf16, XOR-swz

  f32x4 acc[2][4];
#pragma unroll
  for (int i = 0; i < 2; ++i)
#pragma unroll
    for (int j = 0; j < 4; ++j) acc[i][j] = (f32x4)0.f;

  const int am = tid >> 1, ah = tid & 1;
  const int bn = tid >> 2, bq = tid & 3;

  for (int kc = 0; kc < LAT_; kc += 32) {
    __syncthreads();
    {
      const uint4* src = (const uint4*)(latc_bf + (size_t)am * LAT_ + kc + ah * 16);
      const uint4 u0 = src[0];
      const uint4 u1 = src[1];
      const int swz = (am & 7) << 4;
      *(uint4*)(AsB + ((am * 64 + ah * 32) ^ swz)) = u0;
      *(uint4*)(AsB + ((am * 64 + ah * 32 + 16) ^ swz)) = u1;
    }
    {
      const float* src = dyna_w + (size_t)(n0 + bn) * LAT_ + kc + bq * 8;
      const float4 f0 = *(const float4*)(src);
      const float4 f1 = *(const float4*)(src + 4);
      uint4 u;
      u.x = pk2bf(f0.x, f0.y);
      u.y = pk2bf(f0.z, f0.w);
      u.z = pk2bf(f1.x, f1.y);
      u.w = pk2bf(f1.z, f1.w);
      *(uint4*)(BsB + ((bn * 64 + bq * 16) ^ ((bn & 7) << 4))) = u;
    }
    __syncthreads();
    short8 af[2], bf[4];
#pragma unroll
    for (int mt = 0; mt < 2; ++mt) {
      const int rm = wv * 32 + mt * 16 + lr;
      af[mt] = *(const short8*)(AsB + ((rm * 64 + lg * 16) ^ ((rm & 7) << 4)));
    }
#pragma unroll
    for (int nt = 0; nt < 4; ++nt) {
      const int rn = nt * 16 + lr;
      bf[nt] = *(const short8*)(BsB + ((rn * 64 + lg * 16) ^ ((rn & 7) << 4)));
    }
#pragma unroll
    for (int mt = 0; mt < 2; ++mt)
#pragma unroll
      for (int nt = 0; nt < 4; ++nt)
        acc[mt][nt] = __builtin_amdgcn_mfma_f32_16x16x32_bf16(af[mt], bf[nt], acc[mt][nt], 0, 0, 0);
  }

  // epilogue: route each (m,n) to packed weights / biases
#pragma unroll
  for (int nt = 0; nt < 4; ++nt) {
    const int n = n0 + nt * 16 + lr;
    int typ, e_off;
    float addv = 0.f;
    if (n < 12288) { int oc = n / 192; int k = n - oc * 192; typ = 0; e_off = (64 + oc) * 192 + k; }
    else if (n < 12352) { typ = 1; e_off = n - 12288; }
    else if (n < 20544) { int m2 = n - 12352; typ = 2; e_off = WPK_W2 + (m2 >> 6) * 128 + 64 + (m2 & 63); }
    else if (n < 20672) { typ = 3; e_off = 64 + (n - 20544); }
    else if (n < 45248) {
      int m3 = n - 20672; int oc = m3 / 192; int k = m3 - oc * 192;
      typ = 4; e_off = WPK_WS + oc * 192 + k; addv = convs_w[oc * 192 + k];
    } else { typ = 5; e_off = 192 + (n - 45248); }
    const float db = dyna_b[n];
#pragma unroll
    for (int mt = 0; mt < 2; ++mt) {
#pragma unroll
      for (int reg = 0; reg < 4; ++reg) {
        const int cb = wv * 32 + mt * 16 + lg * 4 + reg;
        float v = acc[mt][nt][reg] + db;
        if (typ == 4) v += addv;
        if (typ == 2) v *= 0.1f;
        if (typ == 0 || typ == 2 || typ == 4)
          wpk[(size_t)cb * WPK_STRIDE + e_off] = f2bf(v);
        else
          bias3[(size_t)cb * 320 + e_off] = v;
      }
    }
  }
}

// ---------------- sobel helper (global, branchy — stats only) ----------------
DI void conv9(const float* __restrict__ pl, int h, int w, int H, int W,
              float& vx, float& vy, float& vi) {
  const bool up = h > 0, dn = h < H - 1, lf = w > 0, rt = w < W - 1;
  const float* r0 = pl + (size_t)(h - 1) * W;
  const float* r1 = pl + (size_t)h * W;
  const float* r2 = pl + (size_t)(h + 1) * W;
  float c00 = (up && lf) ? r0[w - 1] : 0.f;
  float c01 = up ? r0[w] : 0.f;
  float c02 = (up && rt) ? r0[w + 1] : 0.f;
  float c10 = lf ? r1[w - 1] : 0.f;
  float c11v = r1[w];
  float c12 = rt ? r1[w + 1] : 0.f;
  float c20 = (dn && lf) ? r2[w - 1] : 0.f;
  float c21 = dn ? r2[w] : 0.f;
  float c22 = (dn && rt) ? r2[w + 1] : 0.f;
  vx = (c02 - c00 + 2.f * (c12 - c10) + (c22 - c20)) * 0.125f;
  vy = (c20 - c00 + 2.f * (c21 - c01) + (c22 - c02)) * 0.125f;
  vi = c11v;
}

// ---------------- stats ----------------
__global__ __launch_bounds__(256) void k_stats(const float* __restrict__ cur,
                                               float* __restrict__ m_s,
                                               float* __restrict__ r_s,
                                               int H, int W, int logW) {
  const int bc = blockIdx.x;
  const int b = bc >> 6, ch = bc & 63;
  const int HW = H * W;
  const float* __restrict__ pl = cur + (size_t)(b * F0_ + ch) * HW;
  const int tid = threadIdx.x;

  float s[6] = {0, 0, 0, 0, 0, 0};
  for (int px = tid; px < HW; px += 256) {
    const int h = px >> logW, w = px & (W - 1);
    float vx, vy, vi;
    conv9(pl, h, w, H, W, vx, vy, vi);
    s[0] += vx; s[1] += vx * vx;
    s[2] += vy; s[3] += vy * vy;
    s[4] += vi; s[5] += vi * vi;
  }
  __shared__ float red[4][6];
#pragma unroll
  for (int i = 0; i < 6; ++i)
#pragma unroll
    for (int off = 32; off > 0; off >>= 1)
      s[i] += __shfl_down(s[i], off, 64);
  const int lane = tid & 63, wv = tid >> 6;
  if (lane == 0) {
#pragma unroll
    for (int i = 0; i < 6; ++i) red[wv][i] = s[i];
  }
  __syncthreads();
  if (tid == 0) {
    float fin[6];
#pragma unroll
    for (int i = 0; i < 6; ++i)
      fin[i] = red[0][i] + red[1][i] + red[2][i] + red[3][i];
    const float inv = 1.0f / (float)HW;
    const float mx = fin[0] * inv, my = fin[2] * inv, mi = fin[4] * inv;
    m_s[b * 192 + ch] = mx;
    m_s[b * 192 + 64 + ch] = my;
    m_s[b * 192 + 128 + ch] = mi;
    r_s[b * 192 + ch] = rsqrtf(fmaxf(fin[1] * inv - mx * mx, 0.f) + 1e-5f);
    r_s[b * 192 + 64 + ch] = rsqrtf(fmaxf(fin[3] * inv - my * my, 0.f) + 1e-5f);
    r_s[b * 192 + 128 + ch] = rsqrtf(fmaxf(fin[5] * inv - mi * mi, 0.f) + 1e-5f);
  }
}

// ---------------- fused main layer: in-LDS p build + MFMA + GLU + out ----------------
__global__ __launch_bounds__(256) void k_main(
    const float* __restrict__ cur, float* __restrict__ nxt,
    const unsigned short* __restrict__ wpk_layer,
    const float* __restrict__ bias3_layer,
    const float* __restrict__ m_s, const float* __restrict__ r_s,
    const float* __restrict__ conv0_b,
    const float* __restrict__ conv1_b,
    const float* __restrict__ noise_w_c,
    const float* __restrict__ leak_ptr,
    int HW, int W, int lwpr, unsigned key0, unsigned key1) {
  const int b = blockIdx.y;
  const int bx = blockIdx.x;
  const int tr = bx >> lwpr;
  const int tc = bx & ((1 << lwpr) - 1);
  const int r0 = tr * 4, c0 = tc * 16;
  const int H = HW >> (lwpr + 4);

  const int tid = threadIdx.x;
  const int wv = tid >> 6, lane = tid & 63;
  const int lg = lane >> 4, lr = lane & 15;

  // union: Ho (halo, 6912B) then Hs (17408B)
  __shared__ __align__(16) unsigned char Ubuf[64 * 136 * 2];
  __shared__ __align__(16) unsigned char Praw[64 * 384];
  __shared__ __align__(16) unsigned char Plre[64 * 384];
  __shared__ float noiseS[64];
  float* Ho = (float*)Ubuf;
  unsigned short* Hs = (unsigned short*)Ubuf;

  const unsigned short* wq = wpk_layer + (size_t)b * WPK_STRIDE;
  const unsigned short* W1 = wq;
  const unsigned short* WS = wq + WPK_WS;
  const unsigned short* W2 = wq + WPK_W2;
  const float* b3 = bias3_layer + (size_t)b * 320;

  // ===== phase A: build p (raw + lrelu) in LDS from out tile + halo =====
  const int c2 = tid & 7, pq = tid >> 3;
  for (int cc = 0; cc < 4; ++cc) {
    if (cc) __syncthreads();
    for (int i = tid; i < 16 * 108; i += 256) {
      const int ch = i / 108;
      const int rem = i - ch * 108;
      const int rr = rem / 18;
      const int cl = rem - rr * 18;
      const int gr = r0 - 1 + rr, gc = c0 - 1 + cl;
      float v = 0.f;
      if (gr >= 0 && gr < H && gc >= 0 && gc < W)
        v = cur[(size_t)(b * F0_ + cc * 16 + ch) * HW + (size_t)gr * W + gc];
      Ho[i] = v;
    }
    __syncthreads();
    // stats for this thread's 2 channels
    float mx[2], rx[2], my[2], ry[2], mi[2], ri[2];
#pragma unroll
    for (int e = 0; e < 2; ++e) {
      const int gch = cc * 16 + 2 * c2 + e;
      mx[e] = m_s[b * 192 + gch];        rx[e] = r_s[b * 192 + gch];
      my[e] = m_s[b * 192 + 64 + gch];   ry[e] = r_s[b * 192 + 64 + gch];
      mi[e] = m_s[b * 192 + 128 + gch];  ri[e] = r_s[b * 192 + 128 + gch];
    }
#pragma unroll
    for (int pp = 0; pp < 2; ++pp) {
      const int pxl = pq * 2 + pp;
      const int r = pxl >> 4, c = pxl & 15;
      float nx[2], ny[2], ni[2];
#pragma unroll
      for (int e = 0; e < 2; ++e) {
        const float* hb = Ho + (2 * c2 + e) * 108 + r * 18 + c;
        const float c00 = hb[0],  c01 = hb[1],  c02 = hb[2];
        const float c10 = hb[18], c11 = hb[19], c12 = hb[20];
        const float c20 = hb[36], c21 = hb[37], c22 = hb[38];
        const float vx = (c02 - c00 + 2.f * (c12 - c10) + (c22 - c20)) * 0.125f;
        const float vy = (c20 - c00 + 2.f * (c21 - c01) + (c22 - c02)) * 0.125f;
        nx[e] = (vx - mx[e]) * rx[e];
        ny[e] = (vy - my[e]) * ry[e];
        ni[e] = (c11 - mi[e]) * ri[e];
      }
      const int swz = (pxl & 7) << 4;
      const int base = pxl * 384 + (cc * 16 + 2 * c2) * 2;
      *(uint32_t*)(Praw + ((base)       ^ swz)) = pk2bf(nx[0], nx[1]);
      *(uint32_t*)(Praw + ((base + 128) ^ swz)) = pk2bf(ny[0], ny[1]);
      *(uint32_t*)(Praw + ((base + 256) ^ swz)) = pk2bf(ni[0], ni[1]);
      *(uint32_t*)(Plre + ((base)       ^ swz)) = pk2bf(nx[0] > 0.f ? nx[0] : 0.2f * nx[0], nx[1] > 0.f ? nx[1] : 0.2f * nx[1]);
      *(uint32_t*)(Plre + ((base + 128) ^ swz)) = pk2bf(ny[0] > 0.f ? ny[0] : 0.2f * ny[0], ny[1] > 0.f ? ny[1] : 0.2f * ny[1]);
      *(uint32_t*)(Plre + ((base + 256) ^ swz)) = pk2bf(ni[0] > 0.f ? ni[0] : 0.2f * ni[0], ni[1] > 0.f ? ni[1] : 0.2f * ni[1]);
    }
  }
  __syncthreads();

  // ===== phase B: GEMM1 (W1 @ lrelu(p)) + GEMM2A (WS @ p), K=192 =====
  const int oc0 = 16 * wv;
  const int oc1 = 64 + 16 * wv;
  f32x4 accH[2][4], accO[2][4];
#pragma unroll
  for (int t = 0; t < 2; ++t)
#pragma unroll
    for (int p = 0; p < 4; ++p) { accH[t][p] = (f32x4)0.f; accO[t][p] = (f32x4)0.f; }

#pragma unroll
  for (int kc = 0; kc < 6; ++kc) {
    const int ko = kc * 32 + lg * 8;
    const short8 a10 = *(const short8*)(W1 + (size_t)(oc0 + lr) * 192 + ko);
    const short8 a11 = *(const short8*)(W1 + (size_t)(oc1 + lr) * 192 + ko);
    const short8 as0 = *(const short8*)(WS + (size_t)(oc0 + lr) * 192 + ko);
    const short8 as1 = *(const short8*)(WS + (size_t)(oc1 + lr) * 192 + ko);
#pragma unroll
    for (int pxt = 0; pxt < 4; ++pxt) {
      const int px = pxt * 16 + lr;
      const int byt = (px * 384 + ko * 2) ^ ((px & 7) << 4);
      const short8 bl = *(const short8*)(Plre + byt);
      const short8 br = *(const short8*)(Praw + byt);
      accH[0][pxt] = __builtin_amdgcn_mfma_f32_16x16x32_bf16(a10, bl, accH[0][pxt], 0, 0, 0);
      accH[1][pxt] = __builtin_amdgcn_mfma_f32_16x16x32_bf16(a11, bl, accH[1][pxt], 0, 0, 0);
      accO[0][pxt] = __builtin_amdgcn_mfma_f32_16x16x32_bf16(as0, br, accO[0][pxt], 0, 0, 0);
      accO[1][pxt] = __builtin_amdgcn_mfma_f32_16x16x32_bf16(as1, br, accO[1][pxt], 0, 0, 0);
    }
  }

  // h = lrelu(acc + bias) -> Hs (overwrites Ho region; safe: Ho last read before the sync above)
#pragma unroll
  for (int ti = 0; ti < 2; ++ti) {
    const int ocb = ti ? oc1 : oc0;
    float bh[4];
#pragma unroll
    for (int r = 0; r < 4; ++r) {
      const int oc = ocb + lg * 4 + r;
      bh[r] = (oc < 64) ? conv0_b[oc] : b3[oc - 64];
    }
#pragma unroll
    for (int pxt = 0; pxt < 4; ++pxt) {
      const int px = pxt * 16 + lr;
#pragma unroll
      for (int rp = 0; rp < 2; ++rp) {
        float h0 = accH[ti][pxt][rp * 2 + 0] + bh[rp * 2 + 0];
        float h1 = accH[ti][pxt][rp * 2 + 1] + bh[rp * 2 + 1];
        h0 = h0 > 0.f ? h0 : 0.2f * h0;
        h1 = h1 > 0.f ? h1 : 0.2f * h1;
        *(uint32_t*)(&Hs[(size_t)px * 136 + ocb + lg * 4 + rp * 2]) = pk2bf(h0, h1);
      }
    }
  }
  if (tid < 64)
    noiseS[tid] = noise_val(key0, key1,
        (unsigned)(b * HW + (r0 + (tid >> 4)) * W + c0 + (tid & 15)));
  __syncthreads();

  // ===== GEMM2B: += W2 @ lrelu(h), K=128 =====
#pragma unroll
  for (int kc = 0; kc < 4; ++kc) {
    const int ko = kc * 32 + lg * 8;
    const short8 a20 = *(const short8*)(W2 + (size_t)(oc0 + lr) * 128 + ko);
    const short8 a21 = *(const short8*)(W2 + (size_t)(oc1 + lr) * 128 + ko);
#pragma unroll
    for (int pxt = 0; pxt < 4; ++pxt) {
      const short8 hb = *(const short8*)(&Hs[(size_t)(pxt * 16 + lr) * 136 + ko]);
      accO[0][pxt] = __builtin_amdgcn_mfma_f32_16x16x32_bf16(a20, hb, accO[0][pxt], 0, 0, 0);
      accO[1][pxt] = __builtin_amdgcn_mfma_f32_16x16x32_bf16(a21, hb, accO[1][pxt], 0, 0, 0);
    }
  }

  // ===== epilogue: bias, GLU, noise, out_new = out_old + lf*val =====
  const float lfv = fminf(fmaxf(leak_ptr[0], 0.001f), 1000.0f);
  float boA[4], boG[4], nw[4];
#pragma unroll
  for (int r = 0; r < 4; ++r) {
    const int oca = oc0 + lg * 4 + r;
    const int ocg = oc1 + lg * 4 + r;
    boA[r] = b3[192 + oca] + 0.1f * (conv1_b[oca] + b3[64 + oca]);
    boG[r] = b3[192 + ocg] + 0.1f * (conv1_b[ocg] + b3[64 + ocg]);
    nw[r] = noise_w_c[oca];
  }
#pragma unroll
  for (int pxt = 0; pxt < 4; ++pxt) {
    const float nz = noiseS[pxt * 16 + lr];
#pragma unroll
    for (int r = 0; r < 4; ++r) {
      const float a = accO[0][pxt][r] + boA[r];
      const float g = accO[1][pxt][r] + boG[r];
      const float og = a * (1.0f / (1.0f + expf(-g)));
      const float val = og + nw[r] * nz;
      const int ch = oc0 + lg * 4 + r;
      const size_t adr = (size_t)(b * F0_ + ch) * HW + (size_t)(r0 + pxt) * W + c0 + lr;
      nxt[adr] = cur[adr] + lfv * val;
    }
  }
}

// ---------------- fused bilinear-2x-resize + gaussian (separable composite) ----------------
__global__ __launch_bounds__(256) void k_upgauss(const float* __restrict__ src,
                                                 float* __restrict__ dst,
                                                 int H, int W, int loOW, int loOHW,
                                                 float ge, float gm) {
  const int idx = blockIdx.x * 256 + threadIdx.x;
  const int OHW = 1 << loOHW;
  if (idx >= B_ * F0_ * OHW) return;
  const int plane = idx >> loOHW;
  const int opx = idx & (OHW - 1);
  const int oh = opx >> loOW, ow = opx & ((1 << loOW) - 1);
  const float g[3] = {ge, gm, ge};

  float wy[3] = {0.f, 0.f, 0.f}, wx[3] = {0.f, 0.f, 0.f};
  const int myi = oh >> 1, mxi = ow >> 1;
#pragma unroll
  for (int d = -1; d <= 1; ++d) {
    {
      const int oo = oh + d;
      if (oo >= 0 && oo < 2 * H) {
        const int i0 = (oo - 1) >> 1;
        const float f = ((oo - 1) & 1) ? 0.75f : 0.25f;
        const int i0c = max(i0, 0), i1c = min(i0 + 1, H - 1);
        wy[i0c - (myi - 1)] += g[d + 1] * (1.f - f);
        wy[i1c - (myi - 1)] += g[d + 1] * f;
      }
    }
    {
      const int oo = ow + d;
      if (oo >= 0 && oo < 2 * W) {
        const int i0 = (oo - 1) >> 1;
        const float f = ((oo - 1) & 1) ? 0.75f : 0.25f;
        const int i0c = max(i0, 0), i1c = min(i0 + 1, W - 1);
        wx[i0c - (mxi - 1)] += g[d + 1] * (1.f - f);
        wx[i1c - (mxi - 1)] += g[d + 1] * f;
      }
    }
  }
  const float* pl = src + (size_t)plane * H * W;
  float acc = 0.f;
#pragma unroll
  for (int i = 0; i < 3; ++i) {
    const int ry = min(max(myi - 1 + i, 0), H - 1);
    const float* rp = pl + (size_t)ry * W;
    float rowv = 0.f;
#pragma unroll
    for (int j = 0; j < 3; ++j) {
      const int rx = min(max(mxi - 1 + j, 0), W - 1);
      rowv = fmaf(wx[j], rp[rx], rowv);
    }
    acc = fmaf(wy[i], rowv, acc);
  }
  dst[idx] = acc;
}

// ---------------- final 1x1 conv + clip ----------------
__global__ __launch_bounds__(256) void k_final(const float* __restrict__ outbuf,
                                               const float* __restrict__ out_w,
                                               const float* __restrict__ out_b,
                                               float* __restrict__ dout) {
  const int idx = blockIdx.x * 256 + threadIdx.x;
  const int px = idx & 16383;
  const int t = idx >> 14;
  const int o = t % 3, b = t / 3;
  const float* src = outbuf + (size_t)b * F0_ * 16384 + px;
  const float* wr = out_w + o * F0_;
  float acc = out_b[o];
#pragma unroll 8
  for (int i = 0; i < F0_; ++i) acc = fmaf(wr[i], src[(size_t)i * 16384], acc);
  dout[idx] = fminf(fmaxf(acc, -1.f), 1.f);
  dout[393216 + idx] = acc;
}

// ---------------- host launch ----------------
extern "C" void kernel_launch(void* const* d_in, const int* in_sizes, int n_in,
                              void* d_out, int out_size, void* d_ws, size_t ws_size,
                              hipStream_t stream) {
  const float* lat       = (const float*)d_in[0];
  const float* seed      = (const float*)d_in[1];
  const float* leak      = (const float*)d_in[2];
  const float* lat_exp_w = (const float*)d_in[3];
  const float* lat_exp_b = (const float*)d_in[4];
  const float* noise_w   = (const float*)d_in[5];
  const float* dyna_w    = (const float*)d_in[6];
  const float* dyna_b    = (const float*)d_in[7];
  const float* conv0_w   = (const float*)d_in[8];
  const float* conv0_b   = (const float*)d_in[9];
  const float* conv1_w   = (const float*)d_in[10];
  const float* conv1_b   = (const float*)d_in[11];
  const float* convs_w   = (const float*)d_in[12];
  const float* out_w     = (const float*)d_in[13];
  const float* out_b     = (const float*)d_in[14];

  float* wsf = (float*)d_ws;
  float* latc = wsf + OFF_LATC;
  float* m_s  = wsf + OFF_MS;
  float* r_s  = wsf + OFF_RS;
  float* b3   = wsf + OFF_B3;
  unsigned short* latc_bf = (unsigned short*)(wsf + OFF_LATCBF);
  float* out0 = wsf + OFF_OUT0;
  float* out1 = wsf + OFF_OUT1;
  unsigned short* wpk = (unsigned short*)(wsf + OFF_WPK);

  uint32_t lk0[NLAY_], lk1[NLAY_];
  for (int c = 0; c < NLAY_; ++c)
    host_tf_cipher(0u, 7u, 0u, (uint32_t)c, lk0[c], lk1[c]);

  const double ga = exp(-0.5);
  const float ge = (float)(ga / (1.0 + 2.0 * ga));
  const float gm = (float)(1.0 / (1.0 + 2.0 * ga));

  k_seed<<<(B_ * F0_ * 256) / 256, 256, 0, stream>>>(seed, out0);
  k_latc<<<NLAY_, 256, 0, stream>>>(lat, lat_exp_w, lat_exp_b, latc, latc_bf);
  k_wstatic<<<NLAY_ * B_, 256, 0, stream>>>(conv0_w, conv1_w, wpk);
  k_ks<<<P_ / 64, 256, 0, stream>>>(latc_bf, dyna_w, dyna_b, convs_w, wpk, b3);

  float* cur = out0;
  float* nxt = out1;
  int H = 16, W = 16, logW = 4;
  for (int c = 0; c < NLAY_; ++c) {
    const int HW = H * W;
    const int lwpr = logW - 4;
    k_stats<<<B_ * F0_, 256, 0, stream>>>(cur, m_s, r_s, H, W, logW);
    k_main<<<dim3(HW / 64, B_), 256, 0, stream>>>(
        cur, nxt,
        wpk + (size_t)c * B_ * WPK_STRIDE, b3 + (size_t)c * B_ * 320,
        m_s, r_s, conv0_b, conv1_b, noise_w + c * F0_, leak,
        HW, W, lwpr, lk0[c], lk1[c]);
    { float* t = cur; cur = nxt; nxt = t; }
    if ((c & 3) == 3 && c < NLAY_ - 1) {
      const int n1 = B_ * F0_ * 4 * H * W;
      int loOW = logW + 1, loOHW = 2 * logW + 2;
      k_upgauss<<<(n1 + 255) / 256, 256, 0, stream>>>(cur, nxt, H, W, loOW, loOHW, ge, gm);
      { float* t = cur; cur = nxt; nxt = t; }
      H *= 2; W *= 2; logW += 1;
    }
  }
  k_final<<<(B_ * 3 * 16384) / 256, 256, 0, stream>>>(cur, out_w, out_b,
                                                      (float*)d_out);
  (void)in_sizes; (void)n_in; (void)out_size; (void)ws_size;
}